// Round 1
// 504.913 us; speedup vs baseline: 1.0207x; 1.0207x over previous
//
#include <hip/hip_runtime.h>
#include <math.h>

#define NNODES_FEAT 128   // node input dim
#define HD 128            // H*D = 4*32
#define H 4
#define D 32
#define EDGE_F 16         // edge input dim
#define NEG_SLOPE 0.2f

typedef _Float16 f16;
typedef _Float16 f16x2 __attribute__((ext_vector_type(2)));
typedef _Float16 f16x4 __attribute__((ext_vector_type(4)));
typedef _Float16 f16x8 __attribute__((ext_vector_type(8)));
typedef float f32x4 __attribute__((ext_vector_type(4)));

union ExPack { float2 f; f16x4 h; };

// ---------------- K0: w_eh[k][h] = sum_d W_edge[k*128 + h*32 + d] * attn_edge[h*32+d]
__global__ void k_wedge(const float* __restrict__ W_edge,
                        const float* __restrict__ attn_edge,
                        float* __restrict__ w_eh) {
    int t = threadIdx.x;            // 0..63
    int k = t >> 2;                 // 0..15
    int h = t & 3;                  // 0..3
    float s = 0.f;
    for (int d = 0; d < D; ++d)
        s += W_edge[k * HD + h * D + d] * attn_edge[h * D + d];
    w_eh[k * H + h] = s;
}

// ---------------- K0c: Wt[n][k] = (n<128 ? Wfc[k][n] : Wres[k][n-128]) as fp16
__global__ __launch_bounds__(256) void k_wt(const float* __restrict__ Wfc,
                                            const float* __restrict__ Wres,
                                            f16* __restrict__ Wt) {
    int i = blockIdx.x * 256 + threadIdx.x;    // 0..32767
    int n = i >> 7, k = i & 127;
    float v = (n < 128) ? Wfc[k * HD + n] : Wres[k * HD + (n - 128)];
    Wt[(size_t)n * 128 + k] = (f16)v;
}

// ---------------- K1: MFMA GEMM  A[N,128](fp32) @ Wt^T -> feat16 (cb=0) / out (cb=1)
// block: 256 thr = 4 waves, tile M=64 x Ncols=128, K=128 fully staged
#define LDK 136   // padded leading dim (halves)
__global__ __launch_bounds__(256) void k_gemm_mfma(
    const float* __restrict__ A, const f16* __restrict__ Wt,
    const float* __restrict__ bias, f16* __restrict__ feat16,
    float* __restrict__ out, int N) {
    __shared__ f16 As[64 * LDK];
    __shared__ f16 Bs[128 * LDK];
    int tid = threadIdx.x;
    int wave = tid >> 6, lane = tid & 63;
    int m0 = blockIdx.x * 64;
    int cb = blockIdx.y;

    // stage A tile: 64 rows x 128 floats, convert fp32->fp16 on LDS store
    for (int c = tid; c < 64 * 32; c += 256) {
        int r = c >> 5, cc = (c & 31) * 4;
        int gr = m0 + r;
        float4 v = make_float4(0.f, 0.f, 0.f, 0.f);
        if (gr < N) v = *(const float4*)(A + (size_t)gr * 128 + cc);
        f16x4 h = {(f16)v.x, (f16)v.y, (f16)v.z, (f16)v.w};
        *(f16x4*)(&As[r * LDK + cc]) = h;
    }
    // stage B tile: rows = output cols [cb*128, cb*128+128), each 128 halves
    const f16* Wblk = Wt + (size_t)cb * 128 * 128;
    for (int c = tid; c < 128 * 16; c += 256) {
        int r = c >> 4, cc = (c & 15) * 8;
        float4 v = *(const float4*)(Wblk + (size_t)r * 128 + cc);
        *(float4*)(&Bs[r * LDK + cc]) = v;
    }
    __syncthreads();

    int am = lane & 15, aq = lane >> 4;
    f32x4 acc[8];
#pragma unroll
    for (int nt = 0; nt < 8; ++nt) acc[nt] = (f32x4){0.f, 0.f, 0.f, 0.f};

    int arow = wave * 16 + am;
#pragma unroll
    for (int kc = 0; kc < 4; ++kc) {
        f16x8 a = *(const f16x8*)(&As[arow * LDK + kc * 32 + aq * 8]);
#pragma unroll
        for (int nt = 0; nt < 8; ++nt) {
            f16x8 b = *(const f16x8*)(&Bs[(nt * 16 + am) * LDK + kc * 32 + aq * 8]);
            acc[nt] = __builtin_amdgcn_mfma_f32_16x16x32_f16(a, b, acc[nt], 0, 0, 0);
        }
    }

    // epilogue: D row=(lane>>4)*4+r, col=lane&15 within each 16x16 tile
    int orow0 = m0 + wave * 16 + aq * 4;
    if (cb == 0) {
#pragma unroll
        for (int nt = 0; nt < 8; ++nt) {
            int col = nt * 16 + am;
#pragma unroll
            for (int r = 0; r < 4; ++r) {
                int row = orow0 + r;
                if (row < N) feat16[(size_t)row * 128 + col] = (f16)acc[nt][r];
            }
        }
    } else {
#pragma unroll
        for (int nt = 0; nt < 8; ++nt) {
            int col = nt * 16 + am;
            float bv = bias[col];
#pragma unroll
            for (int r = 0; r < 4; ++r) {
                int row = orow0 + r;
                if (row < N) out[(size_t)row * 128 + col] = acc[nt][r] + bv;
            }
        }
    }
}

// ---------------- K1b: a_src/a_dst [N,H] reductions over feat16
__global__ __launch_bounds__(256) void k_attn_nodes(
    const f16* __restrict__ feat16, const float* __restrict__ attn_src,
    const float* __restrict__ attn_dst, float* __restrict__ a_src,
    float* __restrict__ a_dst, int N) {
    int g = blockIdx.x * 256 + threadIdx.x;
    int n = g >> 2, h = g & 3;
    if (n >= N) return;
    const f16* f = feat16 + (size_t)n * HD + h * D;
    const float* w1 = attn_src + h * D;
    const float* w2 = attn_dst + h * D;
    float s1 = 0.f, s2 = 0.f;
#pragma unroll
    for (int d = 0; d < D; d += 2) {
        f16x2 fv = *(const f16x2*)(f + d);
        float f0 = (float)fv.x, f1 = (float)fv.y;
        s1 += f0 * w1[d] + f1 * w1[d + 1];
        s2 += f0 * w2[d] + f1 * w2[d + 1];
    }
    a_src[n * H + h] = s1;
    a_dst[n * H + h] = s2;
}

// ---------------- K2a: in-degree count + per-edge rank (old value of the atomic)
__global__ __launch_bounds__(256) void k_count(const int* __restrict__ dst,
                                               int* __restrict__ deg,
                                               int* __restrict__ rank, int E) {
    int base = blockIdx.x * 1024 + threadIdx.x;
#pragma unroll
    for (int j = 0; j < 4; ++j) {
        int e = base + j * 256;
        if (e < E) rank[e] = atomicAdd(deg + dst[e], 1);
    }
}

// ---------------- K2b: scan, block partial sums (1024 elems / block)
__global__ __launch_bounds__(256) void k_scan_partial(
    const int* __restrict__ deg, int* __restrict__ partial, int N) {
    __shared__ int sdata[256];
    int t = threadIdx.x;
    int base = blockIdx.x * 1024 + t * 4;
    int s = 0;
#pragma unroll
    for (int j = 0; j < 4; ++j) { int i = base + j; if (i < N) s += deg[i]; }
    sdata[t] = s;
    __syncthreads();
    for (int off = 128; off > 0; off >>= 1) {
        if (t < off) sdata[t] += sdata[t + off];
        __syncthreads();
    }
    if (t == 0) partial[blockIdx.x] = sdata[0];
}

// ---------------- K2c: scan top level (single block), exclusive over partials
__global__ __launch_bounds__(256) void k_scan_top(
    int* __restrict__ partial, int* __restrict__ offs, int nb, int N) {
    __shared__ int sdata[256];
    int t = threadIdx.x;
    int v = (t < nb) ? partial[t] : 0;
    sdata[t] = v;
    __syncthreads();
    for (int off = 1; off < 256; off <<= 1) {
        int add = (t >= off) ? sdata[t - off] : 0;
        __syncthreads();
        sdata[t] += add;
        __syncthreads();
    }
    int excl = (t == 0) ? 0 : sdata[t - 1];
    if (t < nb) partial[t] = excl;
    if (t == nb - 1) offs[N] = sdata[t];   // total = E
}

// ---------------- K2d: final scan; offs aliases deg (in-place, block-local)
__global__ __launch_bounds__(256) void k_scan_final(
    int* __restrict__ deg_offs, const int* __restrict__ partial, int N) {
    __shared__ int sdata[256];
    int t = threadIdx.x;
    int base = blockIdx.x * 1024 + t * 4;
    int v[4]; int s = 0;
#pragma unroll
    for (int j = 0; j < 4; ++j) { int i = base + j; v[j] = (i < N) ? deg_offs[i] : 0; s += v[j]; }
    sdata[t] = s;
    __syncthreads();
    for (int off = 1; off < 256; off <<= 1) {
        int add = (t >= off) ? sdata[t - off] : 0;
        __syncthreads();
        sdata[t] += add;
        __syncthreads();
    }
    int excl = partial[blockIdx.x] + ((t == 0) ? 0 : sdata[t - 1]);
#pragma unroll
    for (int j = 0; j < 4; ++j) {
        int i = base + j;
        if (i < N) { deg_offs[i] = excl; excl += v[j]; }
    }
}

// ---------------- K3: per-edge logits -> exp -> 16B record scatter
// No atomic: pos = offs[dst] + rank[e]. 4 edges/thread, split-phase for MLP.
__global__ __launch_bounds__(256) void k_edge_fill(
    const float* __restrict__ edge_inputs, const int* __restrict__ src,
    const int* __restrict__ dst, const float* __restrict__ w_eh,
    const float* __restrict__ a_src, const float* __restrict__ a_dst,
    const int* __restrict__ offs, const int* __restrict__ rank,
    float4* __restrict__ rec, int E) {
    __shared__ float weh_s[EDGE_F * H];
    if (threadIdx.x < EDGE_F * H) weh_s[threadIdx.x] = w_eh[threadIdx.x];
    __syncthreads();

    int base = blockIdx.x * 1024 + threadIdx.x;

    // phase 1: coalesced loads (independent, all in flight together)
    int sj[4], dj[4], rj[4];
    bool valid[4];
#pragma unroll
    for (int j = 0; j < 4; ++j) {
        int e = base + j * 256;
        valid[j] = (e < E);
        sj[j] = valid[j] ? src[e] : 0;
        dj[j] = valid[j] ? dst[e] : 0;
        rj[j] = valid[j] ? rank[e] : 0;
    }

    // phase 2: L2-resident gathers (a_src/a_dst tables 3.2MB, offs 0.4MB)
    float4 as[4], ad[4];
    int pos[4];
#pragma unroll
    for (int j = 0; j < 4; ++j) {
        as[j] = *(const float4*)(a_src + sj[j] * H);
        ad[j] = *(const float4*)(a_dst + dj[j] * H);
        pos[j] = offs[dj[j]] + rj[j];
    }

    // phase 3: edge-feature dot, combine, exp, scattered 16B store
#pragma unroll
    for (int j = 0; j < 4; ++j) {
        if (!valid[j]) continue;
        int e = base + j * 256;
        const float* x = edge_inputs + (size_t)e * EDGE_F;
        float4 x0 = *(const float4*)(x);
        float4 x1 = *(const float4*)(x + 4);
        float4 x2 = *(const float4*)(x + 8);
        float4 x3 = *(const float4*)(x + 12);
        float xs[16] = {x0.x, x0.y, x0.z, x0.w, x1.x, x1.y, x1.z, x1.w,
                        x2.x, x2.y, x2.z, x2.w, x3.x, x3.y, x3.z, x3.w};
        float ae0 = 0.f, ae1 = 0.f, ae2 = 0.f, ae3 = 0.f;
#pragma unroll
        for (int k = 0; k < EDGE_F; ++k) {
            float xv = xs[k];
            ae0 += xv * weh_s[k * H + 0];
            ae1 += xv * weh_s[k * H + 1];
            ae2 += xv * weh_s[k * H + 2];
            ae3 += xv * weh_s[k * H + 3];
        }
        float ev[H];
        ev[0] = as[j].x + ad[j].x + ae0;
        ev[1] = as[j].y + ad[j].y + ae1;
        ev[2] = as[j].z + ad[j].z + ae2;
        ev[3] = as[j].w + ad[j].w + ae3;
#pragma unroll
        for (int h = 0; h < H; ++h) {
            float t = ev[h];
            t = t > 0.f ? t : NEG_SLOPE * t;
            ev[h] = __expf(t);
        }
        ExPack p;
        p.h = (f16x4){(f16)ev[0], (f16)ev[1], (f16)ev[2], (f16)ev[3]};
        float4 r;
        r.x = __int_as_float(sj[j]);
        r.y = p.f.x;
        r.z = p.f.y;
        r.w = 0.f;
        rec[pos[j]] = r;
    }
}

// ---------------- K4: per-dst aggregation; wave/node, lane = 2 adjacent cols
__global__ __launch_bounds__(256) void k_aggr(
    const f16* __restrict__ feat16, const float4* __restrict__ rec,
    const int* __restrict__ offs, float* __restrict__ out, int N) {
    int wave = threadIdx.x >> 6;
    int lane = threadIdx.x & 63;
    int n = blockIdx.x * 4 + wave;
    if (n >= N) return;
    int beg = offs[n], end = offs[n + 1];
    if (end <= beg) return;                 // no in-edges: out keeps res+bias
    int h = lane >> 4;                      // head of cols {2l, 2l+1}
    size_t c0 = (size_t)2 * lane;
    float num0 = 0.f, num1 = 0.f, den = 0.f;
    int i = beg;
    for (; i + 3 < end; i += 4) {
        float4 r0 = rec[i], r1 = rec[i + 1], r2 = rec[i + 2], r3 = rec[i + 3];
        int s0 = __float_as_int(r0.x), s1 = __float_as_int(r1.x);
        int s2 = __float_as_int(r2.x), s3 = __float_as_int(r3.x);
        f16x2 f0 = *(const f16x2*)(feat16 + (size_t)s0 * HD + c0);
        f16x2 f1 = *(const f16x2*)(feat16 + (size_t)s1 * HD + c0);
        f16x2 f2 = *(const f16x2*)(feat16 + (size_t)s2 * HD + c0);
        f16x2 f3 = *(const f16x2*)(feat16 + (size_t)s3 * HD + c0);
        ExPack p0, p1, p2, p3;
        p0.f = make_float2(r0.y, r0.z);
        p1.f = make_float2(r1.y, r1.z);
        p2.f = make_float2(r2.y, r2.z);
        p3.f = make_float2(r3.y, r3.z);
        float e0 = (float)p0.h[h], e1 = (float)p1.h[h];
        float e2 = (float)p2.h[h], e3 = (float)p3.h[h];
        num0 += e0 * (float)f0.x + e1 * (float)f1.x + e2 * (float)f2.x + e3 * (float)f3.x;
        num1 += e0 * (float)f0.y + e1 * (float)f1.y + e2 * (float)f2.y + e3 * (float)f3.y;
        den += e0 + e1 + e2 + e3;
    }
    for (; i < end; ++i) {
        float4 r0 = rec[i];
        int s0 = __float_as_int(r0.x);
        f16x2 f0 = *(const f16x2*)(feat16 + (size_t)s0 * HD + c0);
        ExPack p0;
        p0.f = make_float2(r0.y, r0.z);
        float e0 = (float)p0.h[h];
        num0 += e0 * (float)f0.x;
        num1 += e0 * (float)f0.y;
        den += e0;
    }
    float inv = 1.f / den;
    size_t o = (size_t)n * HD + c0;
    float2 v = *(float2*)(out + o);
    v.x += num0 * inv;
    v.y += num1 * inv;
    *(float2*)(out + o) = v;
}

extern "C" void kernel_launch(void* const* d_in, const int* in_sizes, int n_in,
                              void* d_out, int out_size, void* d_ws, size_t ws_size,
                              hipStream_t stream) {
    const float* node_inputs = (const float*)d_in[0];
    const float* edge_inputs = (const float*)d_in[1];
    const int*   src         = (const int*)d_in[2];
    const int*   dst         = (const int*)d_in[3];
    const float* W_fc        = (const float*)d_in[4];
    const float* attn_src_p  = (const float*)d_in[5];
    const float* attn_dst_p  = (const float*)d_in[6];
    const float* W_edge      = (const float*)d_in[7];
    const float* attn_edge_p = (const float*)d_in[8];
    const float* W_res       = (const float*)d_in[9];
    const float* bias_p      = (const float*)d_in[10];

    int N = in_sizes[0] / NNODES_FEAT;   // 100000
    int E = in_sizes[2];                 // 1600000

    float* out = (float*)d_out;

    // ---- workspace layout (rec 16B-aligned by construction) ----
    f16*    feat16  = (f16*)d_ws;                          // N*128 halves
    float4* rec     = (float4*)(feat16 + (size_t)N * HD);  // E * 16B
    f16*    Wt      = (f16*)(rec + (size_t)E);             // 256*128 halves
    float*  a_src   = (float*)(Wt + 256 * 128);            // N*4
    float*  a_dst   = a_src + (size_t)N * H;               // N*4
    float*  w_eh    = a_dst + (size_t)N * H;               // 64
    int*    deg     = (int*)(w_eh + 64);                   // N+2 (becomes offs)
    int*    offs    = deg;                                 // alias
    int*    partial = deg + (N + 2);                       // 128
    int*    rank    = partial + 128;                       // E ints

    hipMemsetAsync(deg, 0, (size_t)(N + 2) * sizeof(int), stream);

    // precompute small tensors
    k_wedge<<<1, 64, 0, stream>>>(W_edge, attn_edge_p, w_eh);
    k_wt<<<(256 * 128) / 256, 256, 0, stream>>>(W_fc, W_res, Wt);

    // MFMA GEMM (stages fp32 A directly) -> feat16 (cb=0), out = res + bias (cb=1)
    dim3 g1((N + 63) / 64, 2);
    k_gemm_mfma<<<g1, 256, 0, stream>>>(node_inputs, Wt, bias_p, feat16, out, N);

    // per-node attention logits
    int nb = (N * H + 255) / 256;
    k_attn_nodes<<<nb, 256, 0, stream>>>(feat16, attn_src_p, attn_dst_p, a_src, a_dst, N);

    // CSR by dst: count (capturing per-edge rank) + scan
    int eb = (E + 1023) / 1024;
    k_count<<<eb, 256, 0, stream>>>(dst, deg, rank, E);
    int sb = (N + 1023) / 1024;   // 98 blocks
    k_scan_partial<<<sb, 256, 0, stream>>>(deg, partial, N);
    k_scan_top<<<1, 256, 0, stream>>>(partial, offs, sb, N);
    k_scan_final<<<sb, 256, 0, stream>>>(deg, partial, N);

    // edge logits -> exp, scattered into dst-bucketed 16B records (no atomics)
    k_edge_fill<<<eb, 256, 0, stream>>>(edge_inputs, src, dst, w_eh, a_src, a_dst,
                                        offs, rank, rec, E);

    // aggregation
    int ab = (N + 3) / 4;
    k_aggr<<<ab, 256, 0, stream>>>(feat16, rec, offs, out, N);
}

// Round 2
// 455.486 us; speedup vs baseline: 1.1315x; 1.1085x over previous
//
#include <hip/hip_runtime.h>
#include <math.h>

#define NNODES_FEAT 128   // node input dim
#define HD 128            // H*D = 4*32
#define H 4
#define D 32
#define EDGE_F 16         // edge input dim
#define NEG_SLOPE 0.2f

typedef _Float16 f16;
typedef _Float16 f16x2 __attribute__((ext_vector_type(2)));
typedef _Float16 f16x4 __attribute__((ext_vector_type(4)));
typedef _Float16 f16x8 __attribute__((ext_vector_type(8)));
typedef float f32x4 __attribute__((ext_vector_type(4)));

union ExPack { float2 f; f16x4 h; };

// ---------------- K0: w_eh[k][h] = sum_d W_edge[k*128 + h*32 + d] * attn_edge[h*32+d]
__global__ void k_wedge(const float* __restrict__ W_edge,
                        const float* __restrict__ attn_edge,
                        float* __restrict__ w_eh) {
    int t = threadIdx.x;            // 0..63
    int k = t >> 2;                 // 0..15
    int h = t & 3;                  // 0..3
    float s = 0.f;
    for (int d = 0; d < D; ++d)
        s += W_edge[k * HD + h * D + d] * attn_edge[h * D + d];
    w_eh[k * H + h] = s;
}

// ---------------- K0c: Wt[n][k] = (n<128 ? Wfc[k][n] : Wres[k][n-128]) as fp16
__global__ __launch_bounds__(256) void k_wt(const float* __restrict__ Wfc,
                                            const float* __restrict__ Wres,
                                            f16* __restrict__ Wt) {
    int i = blockIdx.x * 256 + threadIdx.x;    // 0..32767
    int n = i >> 7, k = i & 127;
    float v = (n < 128) ? Wfc[k * HD + n] : Wres[k * HD + (n - 128)];
    Wt[(size_t)n * 128 + k] = (f16)v;
}

// ---------------- K1: MFMA GEMM  A[N,128](fp32) @ Wt^T -> feat16 (half0) / out (half1)
// block: 256 thr = 4 waves, tile M=64 x Ncols=128, K=128 fully staged.
// A staged ONCE; B restaged for the second 128-col half (saves 51 MB A fetch).
#define LDK 136   // padded leading dim (halves)
__global__ __launch_bounds__(256) void k_gemm_mfma(
    const float* __restrict__ A, const f16* __restrict__ Wt,
    const float* __restrict__ bias, f16* __restrict__ feat16,
    float* __restrict__ out, int N) {
    __shared__ f16 As[64 * LDK];
    __shared__ f16 Bs[128 * LDK];
    int tid = threadIdx.x;
    int wave = tid >> 6, lane = tid & 63;
    int m0 = blockIdx.x * 64;

    // stage A tile: 64 rows x 128 floats, convert fp32->fp16 on LDS store
    for (int c = tid; c < 64 * 32; c += 256) {
        int r = c >> 5, cc = (c & 31) * 4;
        int gr = m0 + r;
        float4 v = make_float4(0.f, 0.f, 0.f, 0.f);
        if (gr < N) v = *(const float4*)(A + (size_t)gr * 128 + cc);
        f16x4 h = {(f16)v.x, (f16)v.y, (f16)v.z, (f16)v.w};
        *(f16x4*)(&As[r * LDK + cc]) = h;
    }

    int am = lane & 15, aq = lane >> 4;
    int arow = wave * 16 + am;
    int orow0 = m0 + wave * 16 + aq * 4;

    for (int cb = 0; cb < 2; ++cb) {
        if (cb) __syncthreads();   // previous compute done reading Bs
        // stage B half: rows = output cols [cb*128, cb*128+128), each 128 halves
        const f16* Wblk = Wt + (size_t)cb * 128 * 128;
        for (int c = tid; c < 128 * 16; c += 256) {
            int r = c >> 4, cc = (c & 15) * 8;
            float4 v = *(const float4*)(Wblk + (size_t)r * 128 + cc);
            *(float4*)(&Bs[r * LDK + cc]) = v;
        }
        __syncthreads();

        f32x4 acc[8];
#pragma unroll
        for (int nt = 0; nt < 8; ++nt) acc[nt] = (f32x4){0.f, 0.f, 0.f, 0.f};
#pragma unroll
        for (int kc = 0; kc < 4; ++kc) {
            f16x8 a = *(const f16x8*)(&As[arow * LDK + kc * 32 + aq * 8]);
#pragma unroll
            for (int nt = 0; nt < 8; ++nt) {
                f16x8 b = *(const f16x8*)(&Bs[(nt * 16 + am) * LDK + kc * 32 + aq * 8]);
                acc[nt] = __builtin_amdgcn_mfma_f32_16x16x32_f16(a, b, acc[nt], 0, 0, 0);
            }
        }

        // epilogue: D row=(lane>>4)*4+r, col=lane&15 within each 16x16 tile
        if (cb == 0) {
#pragma unroll
            for (int nt = 0; nt < 8; ++nt) {
                int col = nt * 16 + am;
#pragma unroll
                for (int r = 0; r < 4; ++r) {
                    int row = orow0 + r;
                    if (row < N) feat16[(size_t)row * 128 + col] = (f16)acc[nt][r];
                }
            }
        } else {
#pragma unroll
            for (int nt = 0; nt < 8; ++nt) {
                int col = nt * 16 + am;
                float bv = bias[col];
#pragma unroll
                for (int r = 0; r < 4; ++r) {
                    int row = orow0 + r;
                    if (row < N) out[(size_t)row * 128 + col] = acc[nt][r] + bv;
                }
            }
        }
    }
}

// ---------------- K1b: a_src/a_dst [N,H] reductions over feat16
__global__ __launch_bounds__(256) void k_attn_nodes(
    const f16* __restrict__ feat16, const float* __restrict__ attn_src,
    const float* __restrict__ attn_dst, float* __restrict__ a_src,
    float* __restrict__ a_dst, int N) {
    int g = blockIdx.x * 256 + threadIdx.x;
    int n = g >> 2, h = g & 3;
    if (n >= N) return;
    const f16* f = feat16 + (size_t)n * HD + h * D;
    const float* w1 = attn_src + h * D;
    const float* w2 = attn_dst + h * D;
    float s1 = 0.f, s2 = 0.f;
#pragma unroll
    for (int d = 0; d < D; d += 2) {
        f16x2 fv = *(const f16x2*)(f + d);
        float f0 = (float)fv.x, f1 = (float)fv.y;
        s1 += f0 * w1[d] + f1 * w1[d + 1];
        s2 += f0 * w2[d] + f1 * w2[d + 1];
    }
    a_src[n * H + h] = s1;
    a_dst[n * H + h] = s2;
}

// ---------------- K2a: in-degree count + rank + edge MLP (a_edge -> f16x4)
// Streams edge_inputs coalesced (independent loads, trivially latency-tolerant).
__global__ __launch_bounds__(256) void k_count_mlp(
    const float* __restrict__ edge_inputs, const int* __restrict__ dst,
    const float* __restrict__ w_eh, int* __restrict__ deg,
    int* __restrict__ rank, float2* __restrict__ ae16, int E) {
    __shared__ float weh_s[EDGE_F * H];
    if (threadIdx.x < EDGE_F * H) weh_s[threadIdx.x] = w_eh[threadIdx.x];
    __syncthreads();

    int base = blockIdx.x * 512 + threadIdx.x;
    int e0 = base, e1 = base + 256;
    bool v0 = e0 < E, v1 = e1 < E;

    int d0 = v0 ? dst[e0] : 0;
    int d1 = v1 ? dst[e1] : 0;

    // issue all MLP input loads (independent)
    float4 xa[4], xb[4];
    if (v0) {
        const float* x = edge_inputs + (size_t)e0 * EDGE_F;
        xa[0] = *(const float4*)(x);      xa[1] = *(const float4*)(x + 4);
        xa[2] = *(const float4*)(x + 8);  xa[3] = *(const float4*)(x + 12);
    }
    if (v1) {
        const float* x = edge_inputs + (size_t)e1 * EDGE_F;
        xb[0] = *(const float4*)(x);      xb[1] = *(const float4*)(x + 4);
        xb[2] = *(const float4*)(x + 8);  xb[3] = *(const float4*)(x + 12);
    }

    int r0 = v0 ? atomicAdd(deg + d0, 1) : 0;
    int r1 = v1 ? atomicAdd(deg + d1, 1) : 0;

    if (v0) {
        float ae0 = 0.f, ae1 = 0.f, ae2 = 0.f, ae3 = 0.f;
        const float* xs = (const float*)xa;
#pragma unroll
        for (int k = 0; k < EDGE_F; ++k) {
            float xv = xs[k];
            ae0 += xv * weh_s[k * H + 0];
            ae1 += xv * weh_s[k * H + 1];
            ae2 += xv * weh_s[k * H + 2];
            ae3 += xv * weh_s[k * H + 3];
        }
        ExPack p;
        p.h = (f16x4){(f16)ae0, (f16)ae1, (f16)ae2, (f16)ae3};
        ae16[e0] = p.f;
        rank[e0] = r0;
    }
    if (v1) {
        float ae0 = 0.f, ae1 = 0.f, ae2 = 0.f, ae3 = 0.f;
        const float* xs = (const float*)xb;
#pragma unroll
        for (int k = 0; k < EDGE_F; ++k) {
            float xv = xs[k];
            ae0 += xv * weh_s[k * H + 0];
            ae1 += xv * weh_s[k * H + 1];
            ae2 += xv * weh_s[k * H + 2];
            ae3 += xv * weh_s[k * H + 3];
        }
        ExPack p;
        p.h = (f16x4){(f16)ae0, (f16)ae1, (f16)ae2, (f16)ae3};
        ae16[e1] = p.f;
        rank[e1] = r1;
    }
}

// ---------------- K2b: scan, block partial sums (1024 elems / block)
__global__ __launch_bounds__(256) void k_scan_partial(
    const int* __restrict__ deg, int* __restrict__ partial, int N) {
    __shared__ int sdata[256];
    int t = threadIdx.x;
    int base = blockIdx.x * 1024 + t * 4;
    int s = 0;
#pragma unroll
    for (int j = 0; j < 4; ++j) { int i = base + j; if (i < N) s += deg[i]; }
    sdata[t] = s;
    __syncthreads();
    for (int off = 128; off > 0; off >>= 1) {
        if (t < off) sdata[t] += sdata[t + off];
        __syncthreads();
    }
    if (t == 0) partial[blockIdx.x] = sdata[0];
}

// ---------------- K2c: scan top level (single block), exclusive over partials
__global__ __launch_bounds__(256) void k_scan_top(
    int* __restrict__ partial, int* __restrict__ offs, int nb, int N) {
    __shared__ int sdata[256];
    int t = threadIdx.x;
    int v = (t < nb) ? partial[t] : 0;
    sdata[t] = v;
    __syncthreads();
    for (int off = 1; off < 256; off <<= 1) {
        int add = (t >= off) ? sdata[t - off] : 0;
        __syncthreads();
        sdata[t] += add;
        __syncthreads();
    }
    int excl = (t == 0) ? 0 : sdata[t - 1];
    if (t < nb) partial[t] = excl;
    if (t == nb - 1) offs[N] = sdata[t];   // total = E
}

// ---------------- K2d: final scan; offs aliases deg (in-place, block-local)
__global__ __launch_bounds__(256) void k_scan_final(
    int* __restrict__ deg_offs, const int* __restrict__ partial, int N) {
    __shared__ int sdata[256];
    int t = threadIdx.x;
    int base = blockIdx.x * 1024 + t * 4;
    int v[4]; int s = 0;
#pragma unroll
    for (int j = 0; j < 4; ++j) { int i = base + j; v[j] = (i < N) ? deg_offs[i] : 0; s += v[j]; }
    sdata[t] = s;
    __syncthreads();
    for (int off = 1; off < 256; off <<= 1) {
        int add = (t >= off) ? sdata[t - off] : 0;
        __syncthreads();
        sdata[t] += add;
        __syncthreads();
    }
    int excl = partial[blockIdx.x] + ((t == 0) ? 0 : sdata[t - 1]);
#pragma unroll
    for (int j = 0; j < 4; ++j) {
        int i = base + j;
        if (i < N) { deg_offs[i] = excl; excl += v[j]; }
    }
}

// ---------------- K3: per-edge combine -> exp -> 16B record scatter
// ae precomputed (8B/edge). pos = offs[dst] + rank. 2 edges/thread, split-phase.
__global__ __launch_bounds__(256) void k_edge_fill(
    const int* __restrict__ src, const int* __restrict__ dst,
    const int* __restrict__ rank, const float2* __restrict__ ae16,
    const float* __restrict__ a_src, const float* __restrict__ a_dst,
    const int* __restrict__ offs, float4* __restrict__ rec, int E) {
    int base = blockIdx.x * 512 + threadIdx.x;
    int e0 = base, e1 = base + 256;
    bool v0 = e0 < E, v1 = e1 < E;

    // phase 1: coalesced loads, all independent
    int s0 = v0 ? src[e0] : 0, s1 = v1 ? src[e1] : 0;
    int d0 = v0 ? dst[e0] : 0, d1 = v1 ? dst[e1] : 0;
    int r0 = v0 ? rank[e0] : 0, r1 = v1 ? rank[e1] : 0;
    float2 q0 = v0 ? ae16[e0] : make_float2(0.f, 0.f);
    float2 q1 = v1 ? ae16[e1] : make_float2(0.f, 0.f);

    // phase 2: L2-resident gathers
    float4 as0 = *(const float4*)(a_src + s0 * H);
    float4 as1 = *(const float4*)(a_src + s1 * H);
    float4 ad0 = *(const float4*)(a_dst + d0 * H);
    float4 ad1 = *(const float4*)(a_dst + d1 * H);
    int p0 = offs[d0] + r0;
    int p1 = offs[d1] + r1;

    // phase 3: combine, leaky, exp, pack, scatter
    if (v0) {
        ExPack qa; qa.f = q0;
        float ev[H];
        ev[0] = as0.x + ad0.x + (float)qa.h[0];
        ev[1] = as0.y + ad0.y + (float)qa.h[1];
        ev[2] = as0.z + ad0.z + (float)qa.h[2];
        ev[3] = as0.w + ad0.w + (float)qa.h[3];
#pragma unroll
        for (int h = 0; h < H; ++h) {
            float t = ev[h];
            t = t > 0.f ? t : NEG_SLOPE * t;
            ev[h] = __expf(t);
        }
        ExPack p;
        p.h = (f16x4){(f16)ev[0], (f16)ev[1], (f16)ev[2], (f16)ev[3]};
        float4 r;
        r.x = __int_as_float(s0);
        r.y = p.f.x;
        r.z = p.f.y;
        r.w = 0.f;
        rec[p0] = r;
    }
    if (v1) {
        ExPack qa; qa.f = q1;
        float ev[H];
        ev[0] = as1.x + ad1.x + (float)qa.h[0];
        ev[1] = as1.y + ad1.y + (float)qa.h[1];
        ev[2] = as1.z + ad1.z + (float)qa.h[2];
        ev[3] = as1.w + ad1.w + (float)qa.h[3];
#pragma unroll
        for (int h = 0; h < H; ++h) {
            float t = ev[h];
            t = t > 0.f ? t : NEG_SLOPE * t;
            ev[h] = __expf(t);
        }
        ExPack p;
        p.h = (f16x4){(f16)ev[0], (f16)ev[1], (f16)ev[2], (f16)ev[3]};
        float4 r;
        r.x = __int_as_float(s1);
        r.y = p.f.x;
        r.z = p.f.y;
        r.w = 0.f;
        rec[p1] = r;
    }
}

// ---------------- K4: per-dst aggregation; wave/node, lane = 2 adjacent cols
// e-extraction via explicit select+shift (no dynamic vector index).
__device__ __forceinline__ float exsel(float a, float b, int hword, int hshift) {
    unsigned u = __float_as_uint(hword ? b : a);
    unsigned short us = (unsigned short)(u >> hshift);
    f16 hv;
    __builtin_memcpy(&hv, &us, 2);
    return (float)hv;
}

__global__ __launch_bounds__(256) void k_aggr(
    const f16* __restrict__ feat16, const float4* __restrict__ rec,
    const int* __restrict__ offs, float* __restrict__ out, int N) {
    int wave = threadIdx.x >> 6;
    int lane = threadIdx.x & 63;
    int n = blockIdx.x * 4 + wave;
    if (n >= N) return;
    int beg = offs[n], end = offs[n + 1];
    if (end <= beg) return;                 // no in-edges: out keeps res+bias
    int hword = (lane >> 5) & 1;            // which packed float holds our f16
    int hshift = ((lane >> 4) & 1) * 16;    // which half of it
    size_t c0 = (size_t)2 * lane;
    float num0 = 0.f, num1 = 0.f, den = 0.f;
    int i = beg;
    for (; i + 3 < end; i += 4) {
        float4 r0 = rec[i], r1 = rec[i + 1], r2 = rec[i + 2], r3 = rec[i + 3];
        int s0 = __float_as_int(r0.x), s1 = __float_as_int(r1.x);
        int s2 = __float_as_int(r2.x), s3 = __float_as_int(r3.x);
        f16x2 f0 = *(const f16x2*)(feat16 + (size_t)s0 * HD + c0);
        f16x2 f1 = *(const f16x2*)(feat16 + (size_t)s1 * HD + c0);
        f16x2 f2 = *(const f16x2*)(feat16 + (size_t)s2 * HD + c0);
        f16x2 f3 = *(const f16x2*)(feat16 + (size_t)s3 * HD + c0);
        float e0 = exsel(r0.y, r0.z, hword, hshift);
        float e1 = exsel(r1.y, r1.z, hword, hshift);
        float e2 = exsel(r2.y, r2.z, hword, hshift);
        float e3 = exsel(r3.y, r3.z, hword, hshift);
        num0 += e0 * (float)f0.x + e1 * (float)f1.x + e2 * (float)f2.x + e3 * (float)f3.x;
        num1 += e0 * (float)f0.y + e1 * (float)f1.y + e2 * (float)f2.y + e3 * (float)f3.y;
        den += e0 + e1 + e2 + e3;
    }
    for (; i < end; ++i) {
        float4 r0 = rec[i];
        int s0 = __float_as_int(r0.x);
        f16x2 f0 = *(const f16x2*)(feat16 + (size_t)s0 * HD + c0);
        float e0 = exsel(r0.y, r0.z, hword, hshift);
        num0 += e0 * (float)f0.x;
        num1 += e0 * (float)f0.y;
        den += e0;
    }
    float inv = 1.f / den;
    size_t o = (size_t)n * HD + c0;
    float2 v = *(float2*)(out + o);
    v.x += num0 * inv;
    v.y += num1 * inv;
    *(float2*)(out + o) = v;
}

extern "C" void kernel_launch(void* const* d_in, const int* in_sizes, int n_in,
                              void* d_out, int out_size, void* d_ws, size_t ws_size,
                              hipStream_t stream) {
    const float* node_inputs = (const float*)d_in[0];
    const float* edge_inputs = (const float*)d_in[1];
    const int*   src         = (const int*)d_in[2];
    const int*   dst         = (const int*)d_in[3];
    const float* W_fc        = (const float*)d_in[4];
    const float* attn_src_p  = (const float*)d_in[5];
    const float* attn_dst_p  = (const float*)d_in[6];
    const float* W_edge      = (const float*)d_in[7];
    const float* attn_edge_p = (const float*)d_in[8];
    const float* W_res       = (const float*)d_in[9];
    const float* bias_p      = (const float*)d_in[10];

    int N = in_sizes[0] / NNODES_FEAT;   // 100000
    int E = in_sizes[2];                 // 1600000

    float* out = (float*)d_out;

    // ---- workspace layout (rec 16B-aligned by construction) ----
    f16*    feat16  = (f16*)d_ws;                          // N*128 halves
    float4* rec     = (float4*)(feat16 + (size_t)N * HD);  // E * 16B
    f16*    Wt      = (f16*)(rec + (size_t)E);             // 256*128 halves
    float*  a_src   = (float*)(Wt + 256 * 128);            // N*4
    float*  a_dst   = a_src + (size_t)N * H;               // N*4
    float*  w_eh    = a_dst + (size_t)N * H;               // 64
    int*    deg     = (int*)(w_eh + 64);                   // N+2 (becomes offs)
    int*    offs    = deg;                                 // alias
    int*    partial = deg + (N + 2);                       // 128
    int*    rank    = partial + 128;                       // E ints
    float2* ae16    = (float2*)(rank + (size_t)E);         // E * 8B

    hipMemsetAsync(deg, 0, (size_t)(N + 2) * sizeof(int), stream);

    // precompute small tensors
    k_wedge<<<1, 64, 0, stream>>>(W_edge, attn_edge_p, w_eh);
    k_wt<<<(256 * 128) / 256, 256, 0, stream>>>(W_fc, W_res, Wt);

    // MFMA GEMM (stages fp32 A once) -> feat16 (half0), out = res + bias (half1)
    int gb = (N + 63) / 64;
    k_gemm_mfma<<<gb, 256, 0, stream>>>(node_inputs, Wt, bias_p, feat16, out, N);

    // per-node attention logits
    int nb = (N * H + 255) / 256;
    k_attn_nodes<<<nb, 256, 0, stream>>>(feat16, attn_src_p, attn_dst_p, a_src, a_dst, N);

    // CSR by dst: count (capturing rank) + edge MLP fused + scan
    int eb = (E + 511) / 512;
    k_count_mlp<<<eb, 256, 0, stream>>>(edge_inputs, dst, w_eh, deg, rank, ae16, E);
    int sb = (N + 1023) / 1024;   // 98 blocks
    k_scan_partial<<<sb, 256, 0, stream>>>(deg, partial, N);
    k_scan_top<<<1, 256, 0, stream>>>(partial, offs, sb, N);
    k_scan_final<<<sb, 256, 0, stream>>>(deg, partial, N);

    // edge combine -> exp, scattered into dst-bucketed 16B records (no atomics)
    k_edge_fill<<<eb, 256, 0, stream>>>(src, dst, rank, ae16, a_src, a_dst,
                                        offs, rec, E);

    // aggregation
    int ab = (N + 3) / 4;
    k_aggr<<<ab, 256, 0, stream>>>(feat16, rec, offs, out, N);
}